// Round 1
// baseline (436.237 us; speedup 1.0000x reference)
//
#include <hip/hip_runtime.h>
#include <hip/hip_bf16.h>

// Problem constants
#define BATCH 16384
#define BT 8            // batch elements per block
#define NTHREADS 512    // 8 waves

// ws layout (floats): W1t[64][128] | W2t[128][128] | W3t[128][512]
#define W1T_OFF 0
#define W2T_OFF (64*128)
#define W3T_OFF (W2T_OFF + 128*128)
#define WS_FLOATS (W3T_OFF + 128*512)

__device__ __forceinline__ float bf2f(unsigned int u16) {
    unsigned int x = u16 << 16;
    float f; __builtin_memcpy(&f, &x, 4); return f;
}
__device__ __forceinline__ unsigned short f2bf(float f) {
    unsigned int x; __builtin_memcpy(&x, &f, 4);
    x = (x + 0x7FFFu + ((x >> 16) & 1u)) >> 16;
    return (unsigned short)x;
}
__device__ __forceinline__ void unpack8(uint4 q, float* f) {
    f[0] = bf2f(q.x & 0xFFFFu); f[1] = bf2f(q.x >> 16);
    f[2] = bf2f(q.y & 0xFFFFu); f[3] = bf2f(q.y >> 16);
    f[4] = bf2f(q.z & 0xFFFFu); f[5] = bf2f(q.z >> 16);
    f[6] = bf2f(q.w & 0xFFFFu); f[7] = bf2f(q.w >> 16);
}
__device__ __forceinline__ uint4 pack8(const float* f) {
    uint4 q;
    q.x = (unsigned int)f2bf(f[0]) | ((unsigned int)f2bf(f[1]) << 16);
    q.y = (unsigned int)f2bf(f[2]) | ((unsigned int)f2bf(f[3]) << 16);
    q.z = (unsigned int)f2bf(f[4]) | ((unsigned int)f2bf(f[5]) << 16);
    q.w = (unsigned int)f2bf(f[6]) | ((unsigned int)f2bf(f[7]) << 16);
    return q;
}
__device__ __forceinline__ float softplusf(float x) {
    return fmaxf(x, 0.f) + log1pf(expf(-fabsf(x)));
}
__device__ __forceinline__ float sigmoidf(float x) {
    return 1.f / (1.f + expf(-x));
}

// Transpose weights into ws so main-kernel weight loads are coalesced:
// W1t[k][r]=W1[r][k] (64x128), W2t[k][r]=W2[r][k] (128x128), W3t[k][c]=W3[c][k] (128x512)
__global__ void prep_transpose(const float* __restrict__ W1,
                               const float* __restrict__ W2,
                               const float* __restrict__ W3,
                               float* __restrict__ ws) {
    int idx = blockIdx.x * blockDim.x + threadIdx.x;
    if (idx < W2T_OFF) {
        int k = idx >> 7, r = idx & 127;
        ws[idx] = W1[r * 64 + k];
    } else if (idx < W3T_OFF) {
        int i = idx - W2T_OFF;
        int k = i >> 7, r = i & 127;
        ws[idx] = W2[r * 128 + k];
    } else if (idx < WS_FLOATS) {
        int i = idx - W3T_OFF;
        int k = i >> 9, c = i & 511;
        ws[idx] = W3[c * 128 + k];
    }
}

__global__ __launch_bounds__(NTHREADS, 4)
void logncde_main(const float* __restrict__ hg,
                  const float* __restrict__ sigg,
                  const float* __restrict__ b1,
                  const float* __restrict__ b2,
                  const float* __restrict__ b3,
                  const float* __restrict__ ws,
                  float* __restrict__ out) {
    const float* W1t = ws + W1T_OFF;  // [64][128]
    const float* W2t = ws + W2T_OFF;  // [128][128]
    const float* W3t = ws + W3T_OFF;  // [128][512]

    __shared__ float hs[BT][64];                       // inputs
    __shared__ float z1[BT][128];                      // softplus(a1)
    __shared__ float s1[BT][128];                      // sigmoid(a1)
    __shared__ float z2[BT][128];                      // softplus(a2)
    __shared__ float s2[BT][128];                      // sigmoid(a2)
    __shared__ __align__(16) unsigned short Vt[BT][64][8];     // bf16, Vt[e][n][j] = V[j][n]
    __shared__ float sigs[BT][36];                     // raw signatures
    __shared__ float cmat[BT][8][8];                   // cmat[e][j][i] = c[i][j]
    __shared__ __align__(16) unsigned short dZ1t[BT][128][8];  // bf16, [e][k][i]
    __shared__ __align__(16) unsigned short dZ2t[BT][128][8];  // bf16, [e][k][i]

    const int tid = threadIdx.x;
    const int b0 = blockIdx.x * BT;

    // ---- load h tile (coalesced) and signature tile
    {
        int e = tid >> 6, k = tid & 63;
        hs[e][k] = hg[(b0 + e) * 64 + k];
    }
    if (tid < BT * 36) {
        int e = tid / 36, j = tid % 36;
        sigs[e][j] = sigg[(b0 + e) * 36 + j];
    }
    __syncthreads();

    // ---- build antisymmetric coefficient matrix c[i][j] from level-2 sig
    {
        int e = tid >> 6, rem = tid & 63;
        int jf = rem >> 3, ia = rem & 7;
        float v = 0.f;
        if (ia < jf) {
            int p = 7 * ia - ia * (ia - 1) / 2 + (jf - ia - 1);
            v = sigs[e][8 + p];
        } else if (ia > jf) {
            int p = 7 * jf - jf * (jf - 1) / 2 + (ia - jf - 1);
            v = -sigs[e][8 + p];
        }
        cmat[e][jf][ia] = v;
    }

    const int r = tid & 127;
    const int g = tid >> 7;   // 0..3 -> element pair
    const int e0 = g * 2, e1 = g * 2 + 1;

    // ---- fwd1: a1 = W1 h + b1 ; z1 = softplus(a1), s1 = sigmoid(a1)
    {
        float acc0 = 0.f, acc1 = 0.f;
        for (int k = 0; k < 64; ++k) {
            float w = W1t[k * 128 + r];
            acc0 += w * hs[e0][k];
            acc1 += w * hs[e1][k];
        }
        float bb = b1[r];
        float a0 = acc0 + bb, a1v = acc1 + bb;
        z1[e0][r] = softplusf(a0);  s1[e0][r] = sigmoidf(a0);
        z1[e1][r] = softplusf(a1v); s1[e1][r] = sigmoidf(a1v);
    }
    __syncthreads();

    // ---- fwd2: a2 = W2 z1 + b2
    {
        float acc0 = 0.f, acc1 = 0.f;
        for (int k = 0; k < 128; ++k) {
            float w = W2t[k * 128 + r];
            acc0 += w * z1[e0][k];
            acc1 += w * z1[e1][k];
        }
        float bb = b2[r];
        float a0 = acc0 + bb, a1v = acc1 + bb;
        z2[e0][r] = softplusf(a0);  s2[e0][r] = sigmoidf(a0);
        z2[e1][r] = softplusf(a1v); s2[e1][r] = sigmoidf(a1v);
    }
    __syncthreads();

    // ---- fwd3: V = tanh(W3 z2 + b3), stored transposed bf16 Vt[e][n][j]
    {
        float acc[4][2] = {};
        for (int k = 0; k < 128; ++k) {
            float x0 = z2[e0][k], x1 = z2[e1][k];
            #pragma unroll
            for (int cc = 0; cc < 4; ++cc) {
                float w = W3t[k * 512 + cc * 128 + r];
                acc[cc][0] += w * x0;
                acc[cc][1] += w * x1;
            }
        }
        #pragma unroll
        for (int cc = 0; cc < 4; ++cc) {
            int c = cc * 128 + r;
            float bb = b3[c];
            int jf = c >> 6, n = c & 63;
            Vt[e0][n][jf] = f2bf(tanhf(acc[cc][0] + bb));
            Vt[e1][n][jf] = f2bf(tanhf(acc[cc][1] + bb));
        }
    }
    __syncthreads();

    // ---- jvp1: dA1[i][r] = sum_k W1[r][k] * V[i][k]; dZ1 = s1 * dA1 (8 dirs at once)
    {
        float acc[2][8] = {};
        for (int k = 0; k < 64; ++k) {
            float w = W1t[k * 128 + r];
            #pragma unroll
            for (int eh = 0; eh < 2; ++eh) {
                int e = e0 + eh;
                uint4 q = *reinterpret_cast<const uint4*>(&Vt[e][k][0]);
                float t8[8]; unpack8(q, t8);
                #pragma unroll
                for (int i = 0; i < 8; ++i) acc[eh][i] += w * t8[i];
            }
        }
        #pragma unroll
        for (int eh = 0; eh < 2; ++eh) {
            int e = e0 + eh;
            float s = s1[e][r];
            float v8[8];
            #pragma unroll
            for (int i = 0; i < 8; ++i) v8[i] = s * acc[eh][i];
            *reinterpret_cast<uint4*>(&dZ1t[e][r][0]) = pack8(v8);
        }
    }
    __syncthreads();

    // ---- jvp2: dA2[i][r] = sum_k W2[r][k] * dZ1[i][k]; dZ2 = s2 * dA2
    {
        float acc[2][8] = {};
        for (int k = 0; k < 128; ++k) {
            float w = W2t[k * 128 + r];
            #pragma unroll
            for (int eh = 0; eh < 2; ++eh) {
                int e = e0 + eh;
                uint4 q = *reinterpret_cast<const uint4*>(&dZ1t[e][k][0]);
                float t8[8]; unpack8(q, t8);
                #pragma unroll
                for (int i = 0; i < 8; ++i) acc[eh][i] += w * t8[i];
            }
        }
        #pragma unroll
        for (int eh = 0; eh < 2; ++eh) {
            int e = e0 + eh;
            float s = s2[e][r];
            float v8[8];
            #pragma unroll
            for (int i = 0; i < 8; ++i) v8[i] = s * acc[eh][i];
            *reinterpret_cast<uint4*>(&dZ2t[e][r][0]) = pack8(v8);
        }
    }
    __syncthreads();

    // ---- jvp3 + contraction. Thread owns (element e, output col n), all 8 fields j,
    // all 8 dirs i: acc[j][i] = dA3_i[j*64+n] = sum_k W3[j*64+n][k] * dZ2[i][k]
    {
        int n = tid & 63;
        int e = tid >> 6;   // wave-aligned: one wave per element
        float acc[8][8] = {};
        for (int k = 0; k < 128; ++k) {
            uint4 q = *reinterpret_cast<const uint4*>(&dZ2t[e][k][0]);
            float dz[8]; unpack8(q, dz);
            #pragma unroll
            for (int j = 0; j < 8; ++j) {
                float w = W3t[k * 512 + j * 64 + n];
                #pragma unroll
                for (int i = 0; i < 8; ++i) acc[j][i] += w * dz[i];
            }
        }
        // out[n] = sum_i sig1[i] V[i][n]
        //        + sum_j (1 - V[j][n]^2) * sum_i c[i][j] * dA3_i[j][n]
        float partial = 0.f;
        #pragma unroll
        for (int j = 0; j < 8; ++j) {
            float vj = bf2f(Vt[e][n][j]);
            float m = 1.f - vj * vj;
            float s = 0.f;
            #pragma unroll
            for (int i = 0; i < 8; ++i) s += cmat[e][j][i] * acc[j][i];
            partial += m * s;
        }
        float lvl1 = 0.f;
        #pragma unroll
        for (int i = 0; i < 8; ++i) lvl1 += sigs[e][i] * bf2f(Vt[e][n][i]);
        out[(b0 + e) * 64 + n] = lvl1 + partial;
    }
}

extern "C" void kernel_launch(void* const* d_in, const int* in_sizes, int n_in,
                              void* d_out, int out_size, void* d_ws, size_t ws_size,
                              hipStream_t stream) {
    const float* hg  = (const float*)d_in[0];
    const float* sg  = (const float*)d_in[1];
    const float* W1  = (const float*)d_in[2];
    const float* b1  = (const float*)d_in[3];
    const float* W2  = (const float*)d_in[4];
    const float* b2  = (const float*)d_in[5];
    const float* W3  = (const float*)d_in[6];
    const float* b3  = (const float*)d_in[7];
    float* out = (float*)d_out;
    float* ws  = (float*)d_ws;

    // transpose weights into workspace (352 KB)
    hipLaunchKernelGGL(prep_transpose, dim3((WS_FLOATS + 255) / 256), dim3(256), 0, stream,
                       W1, W2, W3, ws);
    // main fused kernel: 2048 blocks x 512 threads, 8 batch elements each
    hipLaunchKernelGGL(logncde_main, dim3(BATCH / BT), dim3(NTHREADS), 0, stream,
                       hg, sg, b1, b2, b3, ws, out);
}

// Round 2
// 193.020 us; speedup vs baseline: 2.2601x; 2.2601x over previous
//
#include <hip/hip_runtime.h>
#include <hip/hip_bf16.h>

#define BATCH 16384
#define BT 8            // batch elements per block
#define NTHREADS 512    // 8 waves

// ---- workspace layout ----
// fp32 transposed weights (for VALU forward):
//   W1t[64][128] | W2t[128][128] | W3t[128][512]
#define W1T_OFF 0
#define W2T_OFF (64*128)
#define W3T_OFF (W2T_OFF + 128*128)
#define WS_FLOATS (W3T_OFF + 128*512)        // 90112 floats
// bf16 original-layout weights (B^T for MFMA: [n][k]):
//   W1b[128][64] | W2b[128][128] | W3b[512][128]
#define W1B_OFF 0
#define W2B_OFF (128*64)
#define W3B_OFF (W2B_OFF + 128*128)
#define WS_SHORTS (W3B_OFF + 512*128)        // 90112 shorts

// ---- LDS layout (bytes), with phase-based overlays ----
// region A: T[64][72]bf16 (9216) / hs[8][64]f32 (2048, dead early) -> dZ2[64][136]bf16
#define SM_T    0
#define SM_HS   0
#define SM_Z1   9216      // f32 [8][128]
#define SM_Z2   13312     // f32 [8][128]
#define SM_DZ2  0         // bf16 [64][136] overlays T/z1/z2 (all dead by jvp2)
// region B: dZ1 -> pj
#define SM_DZ1  17408     // bf16 [64][136]
#define SM_PJ   17408     // f32 [8][8][64] overlays dZ1 (dead after jvp2)
#define SM_VT   34816     // bf16 [8][64][8]  Vt[e][n][j] = V_j[n]
#define SM_SIG  43008     // f32 [8][36]
#define SM_CM   44160     // f32 [8][8][8]   cm[e][j][i] = c[i][j]
#define SM_S1   46208     // bf16 [8][128]
#define SM_S2   48256     // bf16 [8][128]
#define SM_TOTAL 50304

typedef __attribute__((ext_vector_type(8))) short bf16x8;
typedef __attribute__((ext_vector_type(4))) float f32x4;

__device__ __forceinline__ float bf2f(unsigned int u16) {
    unsigned int x = u16 << 16;
    float f; __builtin_memcpy(&f, &x, 4); return f;
}
__device__ __forceinline__ unsigned short f2bf(float f) {
    unsigned int x; __builtin_memcpy(&x, &f, 4);
    x = (x + 0x7FFFu + ((x >> 16) & 1u)) >> 16;
    return (unsigned short)x;
}
__device__ __forceinline__ void unpack8(uint4 q, float* f) {
    f[0] = bf2f(q.x & 0xFFFFu); f[1] = bf2f(q.x >> 16);
    f[2] = bf2f(q.y & 0xFFFFu); f[3] = bf2f(q.y >> 16);
    f[4] = bf2f(q.z & 0xFFFFu); f[5] = bf2f(q.z >> 16);
    f[6] = bf2f(q.w & 0xFFFFu); f[7] = bf2f(q.w >> 16);
}
__device__ __forceinline__ float softplusf(float x) {
    return fmaxf(x, 0.f) + log1pf(expf(-fabsf(x)));
}
__device__ __forceinline__ float sigmoidf(float x) {
    return 1.f / (1.f + expf(-x));
}
__device__ __forceinline__ bf16x8 ldfrag(const unsigned short* p) {
    return *reinterpret_cast<const bf16x8*>(p);
}

// prep: fp32 transposed copies + bf16 original-layout copies
__global__ void prep_weights(const float* __restrict__ W1,
                             const float* __restrict__ W2,
                             const float* __restrict__ W3,
                             float* __restrict__ ws) {
    int idx = blockIdx.x * blockDim.x + threadIdx.x;
    if (idx < W2T_OFF) {
        int k = idx >> 7, r = idx & 127;
        ws[idx] = W1[r * 64 + k];
    } else if (idx < W3T_OFF) {
        int i = idx - W2T_OFF;
        int k = i >> 7, r = i & 127;
        ws[idx] = W2[r * 128 + k];
    } else if (idx < WS_FLOATS) {
        int i = idx - W3T_OFF;
        int k = i >> 9, c = i & 511;
        ws[idx] = W3[c * 128 + k];
    } else if (idx < WS_FLOATS + WS_SHORTS) {
        int i = idx - WS_FLOATS;
        unsigned short* wb = (unsigned short*)(ws + WS_FLOATS);
        float v;
        if (i < W2B_OFF) v = W1[i];
        else if (i < W3B_OFF) v = W2[i - W2B_OFF];
        else v = W3[i - W3B_OFF];
        wb[i] = f2bf(v);
    }
}

__global__ __launch_bounds__(NTHREADS, 4)
void logncde_main(const float* __restrict__ hg,
                  const float* __restrict__ sigg,
                  const float* __restrict__ b1,
                  const float* __restrict__ b2,
                  const float* __restrict__ b3,
                  const float* __restrict__ wsf,
                  const unsigned short* __restrict__ wsb,
                  float* __restrict__ out) {
    const float* W1t = wsf + W1T_OFF;
    const float* W2t = wsf + W2T_OFF;
    const float* W3t = wsf + W3T_OFF;

    __shared__ __align__(16) char sm[SM_TOTAL];
    float*          hs  = (float*)(sm + SM_HS);            // [8][64]
    float*          z1  = (float*)(sm + SM_Z1);            // [8][128]
    float*          z2  = (float*)(sm + SM_Z2);            // [8][128]
    unsigned short* s1b = (unsigned short*)(sm + SM_S1);   // [8][128]
    unsigned short* s2b = (unsigned short*)(sm + SM_S2);   // [8][128]
    unsigned short* Vt  = (unsigned short*)(sm + SM_VT);   // [8][64][8]
    float*          sigs= (float*)(sm + SM_SIG);           // [8][36]
    float*          cm  = (float*)(sm + SM_CM);            // [8][8][8]
    unsigned short* Tsm = (unsigned short*)(sm + SM_T);    // [64][72]
    unsigned short* dZ1 = (unsigned short*)(sm + SM_DZ1);  // [64][136]
    unsigned short* dZ2 = (unsigned short*)(sm + SM_DZ2);  // [64][136]
    float*          pj  = (float*)(sm + SM_PJ);            // [8][8][64]

    const int tid = threadIdx.x;
    const int b0 = blockIdx.x * BT;

    // ---- load h + signatures
    {
        int e = tid >> 6, k = tid & 63;
        hs[e * 64 + k] = hg[(b0 + e) * 64 + k];
    }
    if (tid < BT * 36) {
        int e = tid / 36, j = tid % 36;
        sigs[e * 36 + j] = sigg[(b0 + e) * 36 + j];
    }
    __syncthreads();

    // ---- cmat[e][j][i] = c[i][j]  (antisymmetric from level-2 sig)
    {
        int e = tid >> 6, rem = tid & 63;
        int jf = rem >> 3, ia = rem & 7;
        float v = 0.f;
        if (ia < jf) {
            int p = 7 * ia - ia * (ia - 1) / 2 + (jf - ia - 1);
            v = sigs[e * 36 + 8 + p];
        } else if (ia > jf) {
            int p = 7 * jf - jf * (jf - 1) / 2 + (ia - jf - 1);
            v = -sigs[e * 36 + 8 + p];
        }
        cm[e * 64 + jf * 8 + ia] = v;
    }

    const int r = tid & 127;
    const int g = tid >> 7;
    const int e0 = g * 2, e1 = g * 2 + 1;

    // ---- fwd1 (fp32 VALU)
    {
        float acc0 = 0.f, acc1 = 0.f;
        for (int k = 0; k < 64; ++k) {
            float w = W1t[k * 128 + r];
            acc0 += w * hs[e0 * 64 + k];
            acc1 += w * hs[e1 * 64 + k];
        }
        float bb = b1[r];
        float a0 = acc0 + bb, a1v = acc1 + bb;
        z1[e0 * 128 + r] = softplusf(a0);  s1b[e0 * 128 + r] = f2bf(sigmoidf(a0));
        z1[e1 * 128 + r] = softplusf(a1v); s1b[e1 * 128 + r] = f2bf(sigmoidf(a1v));
    }
    __syncthreads();

    // ---- fwd2
    {
        float acc0 = 0.f, acc1 = 0.f;
        for (int k = 0; k < 128; ++k) {
            float w = W2t[k * 128 + r];
            acc0 += w * z1[e0 * 128 + k];
            acc1 += w * z1[e1 * 128 + k];
        }
        float bb = b2[r];
        float a0 = acc0 + bb, a1v = acc1 + bb;
        z2[e0 * 128 + r] = softplusf(a0);  s2b[e0 * 128 + r] = f2bf(sigmoidf(a0));
        z2[e1 * 128 + r] = softplusf(a1v); s2b[e1 * 128 + r] = f2bf(sigmoidf(a1v));
    }
    __syncthreads();

    // ---- fwd3: V = tanh(W3 z2 + b3) -> Vt[e][n][j] bf16
    {
        float acc[4][2] = {};
        for (int k = 0; k < 128; ++k) {
            float x0 = z2[e0 * 128 + k], x1 = z2[e1 * 128 + k];
            #pragma unroll
            for (int cc = 0; cc < 4; ++cc) {
                float w = W3t[k * 512 + cc * 128 + r];
                acc[cc][0] += w * x0;
                acc[cc][1] += w * x1;
            }
        }
        #pragma unroll
        for (int cc = 0; cc < 4; ++cc) {
            int c = cc * 128 + r;
            float bb = b3[c];
            int jf = c >> 6, n = c & 63;
            Vt[(e0 * 64 + n) * 8 + jf] = f2bf(tanhf(acc[cc][0] + bb));
            Vt[(e1 * 64 + n) * 8 + jf] = f2bf(tanhf(acc[cc][1] + bb));
        }
    }
    __syncthreads();

    // ---- T-build: T[m=j*8+e][k] = sum_i c[i][j] * V_i[k]   (rows m for MFMA)
    {
        int m = tid >> 3, kg = tid & 7;
        int e = m & 7, j = m >> 3;
        float c8[8];
        #pragma unroll
        for (int i = 0; i < 8; ++i) c8[i] = cm[e * 64 + j * 8 + i];
        unsigned short o[8];
        #pragma unroll
        for (int kk = 0; kk < 8; ++kk) {
            int k = kg * 8 + kk;
            uint4 q = *reinterpret_cast<const uint4*>(&Vt[(e * 64 + k) * 8]);
            float v8[8]; unpack8(q, v8);
            float a = 0.f;
            #pragma unroll
            for (int i = 0; i < 8; ++i) a += c8[i] * v8[i];
            o[kk] = f2bf(a);
        }
        uint4 qo;
        qo.x = (unsigned int)o[0] | ((unsigned int)o[1] << 16);
        qo.y = (unsigned int)o[2] | ((unsigned int)o[3] << 16);
        qo.z = (unsigned int)o[4] | ((unsigned int)o[5] << 16);
        qo.w = (unsigned int)o[6] | ((unsigned int)o[7] << 16);
        *reinterpret_cast<uint4*>(&Tsm[m * 72 + kg * 8]) = qo;
    }
    __syncthreads();

    const int lane = tid & 63;
    const int w = tid >> 6;
    const int r16 = lane & 15;
    const int kb = lane >> 4;
    const int crow = (lane >> 4) * 4;   // C fragment base row

    // ---- jvp1 (MFMA): dA1[64][128] = T[64][64] @ W1^T ; mask s1 -> dZ1 bf16
    {
        int mt = w & 3, nh = w >> 2;
        f32x4 acc[4] = {};
        const unsigned short* Ab = Tsm + (mt * 16 + r16) * 72 + kb * 8;
        const unsigned short* Bb = wsb + W1B_OFF + kb * 8;
        #pragma unroll
        for (int ks = 0; ks < 2; ++ks) {
            bf16x8 a = ldfrag(Ab + ks * 32);
            #pragma unroll
            for (int nt = 0; nt < 4; ++nt) {
                int n = nh * 64 + nt * 16 + r16;
                bf16x8 b = ldfrag(Bb + n * 64 + ks * 32);
                acc[nt] = __builtin_amdgcn_mfma_f32_16x16x32_bf16(a, b, acc[nt], 0, 0, 0);
            }
        }
        #pragma unroll
        for (int nt = 0; nt < 4; ++nt) {
            int col = nh * 64 + nt * 16 + r16;
            #pragma unroll
            for (int rr = 0; rr < 4; ++rr) {
                int row = mt * 16 + crow + rr;
                float v = acc[nt][rr] * bf2f(s1b[(row & 7) * 128 + col]);
                dZ1[row * 136 + col] = f2bf(v);
            }
        }
    }
    __syncthreads();

    // ---- jvp2 (MFMA): dA2 = dZ1 @ W2^T ; mask s2 -> dZ2 bf16
    {
        int mt = w & 3, nh = w >> 2;
        f32x4 acc[4] = {};
        const unsigned short* Ab = dZ1 + (mt * 16 + r16) * 136 + kb * 8;
        const unsigned short* Bb = wsb + W2B_OFF + kb * 8;
        #pragma unroll
        for (int ks = 0; ks < 4; ++ks) {
            bf16x8 a = ldfrag(Ab + ks * 32);
            #pragma unroll
            for (int nt = 0; nt < 4; ++nt) {
                int n = nh * 64 + nt * 16 + r16;
                bf16x8 b = ldfrag(Bb + n * 128 + ks * 32);
                acc[nt] = __builtin_amdgcn_mfma_f32_16x16x32_bf16(a, b, acc[nt], 0, 0, 0);
            }
        }
        __syncthreads();   // all dZ1 reads done before dZ2 (separate region, but pj overlays dZ1 later; keep order strict)
        #pragma unroll
        for (int nt = 0; nt < 4; ++nt) {
            int col = nh * 64 + nt * 16 + r16;
            #pragma unroll
            for (int rr = 0; rr < 4; ++rr) {
                int row = mt * 16 + crow + rr;
                float v = acc[nt][rr] * bf2f(s2b[(row & 7) * 128 + col]);
                dZ2[row * 136 + col] = f2bf(v);
            }
        }
    }
    __syncthreads();

    // ---- jvp3 (MFMA): wave w = field j. C[e][n'] = dZ2[j-rows] @ W3[j*64+n']^T,
    //      masked by tanh' -> pj[j][e][n']
    {
        int j = w;
        int mt = j >> 1, half = j & 1;
        f32x4 acc[4] = {};
        const unsigned short* Ab = dZ2 + (mt * 16 + r16) * 136 + kb * 8;
        const unsigned short* Bb = wsb + W3B_OFF + (j * 64) * 128 + kb * 8;
        #pragma unroll
        for (int ks = 0; ks < 4; ++ks) {
            bf16x8 a = ldfrag(Ab + ks * 32);
            #pragma unroll
            for (int nt = 0; nt < 4; ++nt) {
                bf16x8 b = ldfrag(Bb + (nt * 16 + r16) * 128 + ks * 32);
                acc[nt] = __builtin_amdgcn_mfma_f32_16x16x32_bf16(a, b, acc[nt], 0, 0, 0);
            }
        }
        #pragma unroll
        for (int nt = 0; nt < 4; ++nt) {
            #pragma unroll
            for (int rr = 0; rr < 4; ++rr) {
                int row = crow + rr;               // 0..15 within tile
                if ((row >> 3) == half) {          // keep rows belonging to field j
                    int e = row & 7;
                    int np = nt * 16 + r16;
                    float v = bf2f(Vt[(e * 64 + np) * 8 + j]);
                    pj[(j * 8 + e) * 64 + np] = (1.f - v * v) * acc[nt][rr];
                }
            }
        }
    }
    __syncthreads();

    // ---- reduce: out[e][n'] = sum_i sig1[i] V_i[n'] + sum_j pj[j][e][n']
    {
        int e = tid >> 6, np = tid & 63;
        float s = 0.f;
        #pragma unroll
        for (int j = 0; j < 8; ++j) s += pj[(j * 8 + e) * 64 + np];
        float l1 = 0.f;
        #pragma unroll
        for (int i = 0; i < 8; ++i) l1 += sigs[e * 36 + i] * bf2f(Vt[(e * 64 + np) * 8 + i]);
        out[(b0 + e) * 64 + np] = l1 + s;
    }
}

extern "C" void kernel_launch(void* const* d_in, const int* in_sizes, int n_in,
                              void* d_out, int out_size, void* d_ws, size_t ws_size,
                              hipStream_t stream) {
    const float* hg  = (const float*)d_in[0];
    const float* sg  = (const float*)d_in[1];
    const float* W1  = (const float*)d_in[2];
    const float* b1  = (const float*)d_in[3];
    const float* W2  = (const float*)d_in[4];
    const float* b2  = (const float*)d_in[5];
    const float* W3  = (const float*)d_in[6];
    const float* b3  = (const float*)d_in[7];
    float* outp = (float*)d_out;
    float* ws   = (float*)d_ws;
    const unsigned short* wsb = (const unsigned short*)(ws + WS_FLOATS);

    int prep_items = WS_FLOATS + WS_SHORTS;
    hipLaunchKernelGGL(prep_weights, dim3((prep_items + 255) / 256), dim3(256), 0, stream,
                       W1, W2, W3, ws);
    hipLaunchKernelGGL(logncde_main, dim3(BATCH / BT), dim3(NTHREADS), 0, stream,
                       hg, sg, b1, b2, b3, ws, wsb, outp);
}

// Round 3
// 139.173 us; speedup vs baseline: 3.1345x; 1.3869x over previous
//
#include <hip/hip_runtime.h>
#include <hip/hip_bf16.h>

#define BATCH 16384
#define BT 8            // batch elements per block
#define NTHREADS 512    // 8 waves

// ---- workspace: bf16 weights, original layout (rows = output neuron, cols = k)
#define W1B_OFF 0                       // [128][64]
#define W2B_OFF (128*64)                // [128][128]
#define W3B_OFF (W2B_OFF + 128*128)     // [512][128]
#define WS_SHORTS (W3B_OFF + 512*128)   // 90112 shorts

// ---- LDS layout (bytes), phase overlays
// region A (17408B): hb[16][72]bf16@0, z1b[16][136]@2304, z2b[16][136]@6656
//                    -> dZ1[64][136]bf16@0 -> pj[8][8][64]f32@0
#define SM_HB    0
#define SM_Z1    2304
#define SM_Z2    6656
#define SM_DZ1   0
#define SM_PJ    0
// region B (17408B): Tsm[64][72]bf16 -> dZ2[64][136]bf16
#define SM_T     17408
#define SM_DZ2   17408
#define SM_VT    34816      // bf16 [8][64][8]  Vt[e][n][j] = V_j[n]  (8192B)
#define SM_S1    43008      // bf16 [8][128]    sigmoid(a1)           (2048B)
#define SM_S2    45056      // bf16 [8][128]    sigmoid(a2)           (2048B)
#define SM_SIG   47104      // f32  [8][36]                            (1152B)
#define SM_CM    48256      // f32  [8][72]  cm[e][j*8+i] = c[i][j]   (2304B)
#define SM_TOTAL 50560

typedef __attribute__((ext_vector_type(8))) short bf16x8;
typedef __attribute__((ext_vector_type(4))) float f32x4;

__device__ __forceinline__ float bf2f(unsigned int u16) {
    unsigned int x = u16 << 16;
    float f; __builtin_memcpy(&f, &x, 4); return f;
}
__device__ __forceinline__ unsigned short f2bf(float f) {
    unsigned int x; __builtin_memcpy(&x, &f, 4);
    x = (x + 0x7FFFu + ((x >> 16) & 1u)) >> 16;
    return (unsigned short)x;
}
__device__ __forceinline__ void unpack8(uint4 q, float* f) {
    f[0] = bf2f(q.x & 0xFFFFu); f[1] = bf2f(q.x >> 16);
    f[2] = bf2f(q.y & 0xFFFFu); f[3] = bf2f(q.y >> 16);
    f[4] = bf2f(q.z & 0xFFFFu); f[5] = bf2f(q.z >> 16);
    f[6] = bf2f(q.w & 0xFFFFu); f[7] = bf2f(q.w >> 16);
}
__device__ __forceinline__ float softplusf(float x) {
    return fmaxf(x, 0.f) + log1pf(expf(-fabsf(x)));
}
__device__ __forceinline__ float sigmoidf(float x) {
    return 1.f / (1.f + expf(-x));
}
__device__ __forceinline__ bf16x8 ldfrag(const unsigned short* p) {
    return *reinterpret_cast<const bf16x8*>(p);
}

// prep: bf16 copies of W1, W2, W3 in original [out][k] layout
__global__ void prep_weights(const float* __restrict__ W1,
                             const float* __restrict__ W2,
                             const float* __restrict__ W3,
                             unsigned short* __restrict__ wb) {
    int i = blockIdx.x * blockDim.x + threadIdx.x;
    if (i >= WS_SHORTS) return;
    float v;
    if (i < W2B_OFF) v = W1[i];
    else if (i < W3B_OFF) v = W2[i - W2B_OFF];
    else v = W3[i - W3B_OFF];
    wb[i] = f2bf(v);
}

__global__ __launch_bounds__(NTHREADS, 4)
void logncde_main(const float* __restrict__ hg,
                  const float* __restrict__ sigg,
                  const float* __restrict__ b1,
                  const float* __restrict__ b2,
                  const float* __restrict__ b3,
                  const unsigned short* __restrict__ wsb,
                  float* __restrict__ out) {
    __shared__ __align__(16) char sm[SM_TOTAL];
    unsigned short* hb  = (unsigned short*)(sm + SM_HB);   // [16][72]  rows 8-15 garbage (discarded)
    unsigned short* z1b = (unsigned short*)(sm + SM_Z1);   // [16][136] rows 8-15 garbage
    unsigned short* z2b = (unsigned short*)(sm + SM_Z2);   // [16][136]
    unsigned short* s1b = (unsigned short*)(sm + SM_S1);   // [8][128]
    unsigned short* s2b = (unsigned short*)(sm + SM_S2);   // [8][128]
    unsigned short* Vt  = (unsigned short*)(sm + SM_VT);   // [8][64][8]
    float*          sigs= (float*)(sm + SM_SIG);           // [8][36]
    float*          cm  = (float*)(sm + SM_CM);            // [8][72]
    unsigned short* Tsm = (unsigned short*)(sm + SM_T);    // [64][72]
    unsigned short* dZ1 = (unsigned short*)(sm + SM_DZ1);  // [64][136]
    unsigned short* dZ2 = (unsigned short*)(sm + SM_DZ2);  // [64][136]
    float*          pj  = (float*)(sm + SM_PJ);            // [8][8][64]

    const int tid = threadIdx.x;
    const int b0 = blockIdx.x * BT;

    const int lane = tid & 63;
    const int w = tid >> 6;            // wave id 0..7
    const int r16 = lane & 15;
    const int kb = lane >> 4;          // 0..3 k-block of A/B fragment
    const int crow = (lane >> 4) * 4;  // C fragment base row

    // ---- phase 0: load h (bf16 into MFMA A-tile) + signatures
    {
        int e = tid >> 6, k = tid & 63;
        hb[e * 72 + k] = f2bf(hg[(b0 + e) * 64 + k]);
    }
    if (tid < BT * 36) {
        int e = tid / 36, j = tid % 36;
        sigs[e * 36 + j] = sigg[(b0 + e) * 36 + j];
    }
    __syncthreads();

    // ---- cm[e][j*8+i] = c[i][j] (antisymmetric), padded rows (72 floats)
    {
        int e = tid >> 6, rem = tid & 63;
        int jf = rem >> 3, ia = rem & 7;
        float v = 0.f;
        if (ia < jf) {
            int p = 7 * ia - ia * (ia - 1) / 2 + (jf - ia - 1);
            v = sigs[e * 36 + 8 + p];
        } else if (ia > jf) {
            int p = 7 * jf - jf * (jf - 1) / 2 + (ia - jf - 1);
            v = -sigs[e * 36 + 8 + p];
        }
        cm[e * 72 + jf * 8 + ia] = v;
    }

    // ---- fwd1 (MFMA): a1[8][128] = h @ W1^T; wave w -> n-tile w
    {
        f32x4 acc = {};
        const unsigned short* Ab = hb + r16 * 72 + kb * 8;
        const unsigned short* Bb = wsb + W1B_OFF + (w * 16 + r16) * 64 + kb * 8;
        #pragma unroll
        for (int ks = 0; ks < 2; ++ks) {
            bf16x8 a = ldfrag(Ab + ks * 32);
            bf16x8 b = ldfrag(Bb + ks * 32);
            acc = __builtin_amdgcn_mfma_f32_16x16x32_bf16(a, b, acc, 0, 0, 0);
        }
        if (lane < 32) {
            int col = w * 16 + r16;
            float bb = b1[col];
            #pragma unroll
            for (int rr = 0; rr < 4; ++rr) {
                int e = crow + rr;   // 0..7
                float a1 = acc[rr] + bb;
                z1b[e * 136 + col] = f2bf(softplusf(a1));
                s1b[e * 128 + col] = f2bf(sigmoidf(a1));
            }
        }
    }
    __syncthreads();

    // ---- fwd2 (MFMA): a2 = z1 @ W2^T
    {
        f32x4 acc = {};
        const unsigned short* Ab = z1b + r16 * 136 + kb * 8;
        const unsigned short* Bb = wsb + W2B_OFF + (w * 16 + r16) * 128 + kb * 8;
        #pragma unroll
        for (int ks = 0; ks < 4; ++ks) {
            bf16x8 a = ldfrag(Ab + ks * 32);
            bf16x8 b = ldfrag(Bb + ks * 32);
            acc = __builtin_amdgcn_mfma_f32_16x16x32_bf16(a, b, acc, 0, 0, 0);
        }
        if (lane < 32) {
            int col = w * 16 + r16;
            float bb = b2[col];
            #pragma unroll
            for (int rr = 0; rr < 4; ++rr) {
                int e = crow + rr;
                float a2 = acc[rr] + bb;
                z2b[e * 136 + col] = f2bf(softplusf(a2));
                s2b[e * 128 + col] = f2bf(sigmoidf(a2));
            }
        }
    }
    __syncthreads();

    // ---- fwd3 (MFMA): V = tanh(z2 @ W3^T + b3); wave w = field j=w, cols w*64..w*64+63
    {
        f32x4 acc[4] = {};
        const unsigned short* Ab = z2b + r16 * 136 + kb * 8;
        const unsigned short* Bb = wsb + W3B_OFF + kb * 8;
        #pragma unroll
        for (int ks = 0; ks < 4; ++ks) {
            bf16x8 a = ldfrag(Ab + ks * 32);
            #pragma unroll
            for (int nt = 0; nt < 4; ++nt) {
                bf16x8 b = ldfrag(Bb + (w * 64 + nt * 16 + r16) * 128 + ks * 32);
                acc[nt] = __builtin_amdgcn_mfma_f32_16x16x32_bf16(a, b, acc[nt], 0, 0, 0);
            }
        }
        if (lane < 32) {
            #pragma unroll
            for (int nt = 0; nt < 4; ++nt) {
                int c = w * 64 + nt * 16 + r16;
                float bb = b3[c];
                int n = c & 63;
                #pragma unroll
                for (int rr = 0; rr < 4; ++rr) {
                    int e = crow + rr;
                    float v = tanhf(acc[nt][rr] + bb);
                    Vt[(e * 64 + n) * 8 + w] = f2bf(v);
                }
            }
        }
    }
    __syncthreads();

    // ---- T-build (VALU): T[m=j*8+e][k] = sum_i c[i][j] V_i[k], strided-k (bank-spread)
    {
        int m = tid >> 3;          // 0..63; j = m>>3 == wave
        int e = m & 7, j = m >> 3;
        int kg = tid & 7;
        float c8[8];
        #pragma unroll
        for (int i = 0; i < 8; ++i) c8[i] = cm[e * 72 + j * 8 + i];
        #pragma unroll
        for (int kk = 0; kk < 8; ++kk) {
            int k = kg + kk * 8;
            uint4 q = *reinterpret_cast<const uint4*>(&Vt[(e * 64 + k) * 8]);
            float v8[8]; unpack8(q, v8);
            float a = 0.f;
            #pragma unroll
            for (int i = 0; i < 8; ++i) a += c8[i] * v8[i];
            Tsm[m * 72 + k] = f2bf(a);
        }
    }
    __syncthreads();

    // ---- jvp1 (MFMA): dA1[64][128] = T @ W1^T; mask s1 -> dZ1
    {
        int mt = w & 3, nh = w >> 2;
        f32x4 acc[4] = {};
        const unsigned short* Ab = Tsm + (mt * 16 + r16) * 72 + kb * 8;
        const unsigned short* Bb = wsb + W1B_OFF + kb * 8;
        #pragma unroll
        for (int ks = 0; ks < 2; ++ks) {
            bf16x8 a = ldfrag(Ab + ks * 32);
            #pragma unroll
            for (int nt = 0; nt < 4; ++nt) {
                int n = nh * 64 + nt * 16 + r16;
                bf16x8 b = ldfrag(Bb + n * 64 + ks * 32);
                acc[nt] = __builtin_amdgcn_mfma_f32_16x16x32_bf16(a, b, acc[nt], 0, 0, 0);
            }
        }
        #pragma unroll
        for (int nt = 0; nt < 4; ++nt) {
            int col = nh * 64 + nt * 16 + r16;
            #pragma unroll
            for (int rr = 0; rr < 4; ++rr) {
                int row = mt * 16 + crow + rr;
                float v = acc[nt][rr] * bf2f(s1b[(row & 7) * 128 + col]);
                dZ1[row * 136 + col] = f2bf(v);
            }
        }
    }
    __syncthreads();

    // ---- jvp2 (MFMA): dA2 = dZ1 @ W2^T; mask s2 -> dZ2
    {
        int mt = w & 3, nh = w >> 2;
        f32x4 acc[4] = {};
        const unsigned short* Ab = dZ1 + (mt * 16 + r16) * 136 + kb * 8;
        const unsigned short* Bb = wsb + W2B_OFF + kb * 8;
        #pragma unroll
        for (int ks = 0; ks < 4; ++ks) {
            bf16x8 a = ldfrag(Ab + ks * 32);
            #pragma unroll
            for (int nt = 0; nt < 4; ++nt) {
                int n = nh * 64 + nt * 16 + r16;
                bf16x8 b = ldfrag(Bb + n * 128 + ks * 32);
                acc[nt] = __builtin_amdgcn_mfma_f32_16x16x32_bf16(a, b, acc[nt], 0, 0, 0);
            }
        }
        #pragma unroll
        for (int nt = 0; nt < 4; ++nt) {
            int col = nh * 64 + nt * 16 + r16;
            #pragma unroll
            for (int rr = 0; rr < 4; ++rr) {
                int row = mt * 16 + crow + rr;
                float v = acc[nt][rr] * bf2f(s2b[(row & 7) * 128 + col]);
                dZ2[row * 136 + col] = f2bf(v);
            }
        }
    }
    __syncthreads();

    // ---- jvp3 (MFMA): wave w = field j; masked by tanh' -> pj[j][e][n']
    {
        int j = w;
        int mt = j >> 1, half = j & 1;
        f32x4 acc[4] = {};
        const unsigned short* Ab = dZ2 + (mt * 16 + r16) * 136 + kb * 8;
        const unsigned short* Bb = wsb + W3B_OFF + (j * 64) * 128 + kb * 8;
        #pragma unroll
        for (int ks = 0; ks < 4; ++ks) {
            bf16x8 a = ldfrag(Ab + ks * 32);
            #pragma unroll
            for (int nt = 0; nt < 4; ++nt) {
                bf16x8 b = ldfrag(Bb + (nt * 16 + r16) * 128 + ks * 32);
                acc[nt] = __builtin_amdgcn_mfma_f32_16x16x32_bf16(a, b, acc[nt], 0, 0, 0);
            }
        }
        #pragma unroll
        for (int nt = 0; nt < 4; ++nt) {
            #pragma unroll
            for (int rr = 0; rr < 4; ++rr) {
                int row = crow + rr;               // 0..15 within tile
                if ((row >> 3) == half) {          // rows belonging to field j
                    int e = row & 7;
                    int np = nt * 16 + r16;
                    float v = bf2f(Vt[(e * 64 + np) * 8 + j]);
                    pj[(j * 8 + e) * 64 + np] = (1.f - v * v) * acc[nt][rr];
                }
            }
        }
    }
    __syncthreads();

    // ---- reduce: out[e][n'] = sum_i sig1[i] V_i[n'] + sum_j pj[j][e][n']
    {
        int e = tid >> 6, np = tid & 63;
        uint4 q = *reinterpret_cast<const uint4*>(&Vt[(e * 64 + np) * 8]);
        float v8[8]; unpack8(q, v8);
        float s = 0.f;
        #pragma unroll
        for (int j = 0; j < 8; ++j) s += pj[(j * 8 + e) * 64 + np];
        float l1 = 0.f;
        #pragma unroll
        for (int i = 0; i < 8; ++i) l1 += sigs[e * 36 + i] * v8[i];
        out[(b0 + e) * 64 + np] = l1 + s;
    }
}

extern "C" void kernel_launch(void* const* d_in, const int* in_sizes, int n_in,
                              void* d_out, int out_size, void* d_ws, size_t ws_size,
                              hipStream_t stream) {
    const float* hg  = (const float*)d_in[0];
    const float* sg  = (const float*)d_in[1];
    const float* W1  = (const float*)d_in[2];
    const float* b1  = (const float*)d_in[3];
    const float* W2  = (const float*)d_in[4];
    const float* b2  = (const float*)d_in[5];
    const float* W3  = (const float*)d_in[6];
    const float* b3  = (const float*)d_in[7];
    float* outp = (float*)d_out;
    unsigned short* wsb = (unsigned short*)d_ws;

    hipLaunchKernelGGL(prep_weights, dim3((WS_SHORTS + 255) / 256), dim3(256), 0, stream,
                       W1, W2, W3, wsb);
    hipLaunchKernelGGL(logncde_main, dim3(BATCH / BT), dim3(NTHREADS), 0, stream,
                       hg, sg, b1, b2, b3, wsb, outp);
}

// Round 4
// 126.463 us; speedup vs baseline: 3.4495x; 1.1005x over previous
//
#include <hip/hip_runtime.h>
#include <hip/hip_bf16.h>

#define BATCH 16384
#define BT 8            // batch elements per block
#define NTHREADS 512    // 8 waves

// ---- workspace: bf16 weights, original layout (rows = output neuron, cols = k)
#define W1B_OFF 0                       // [128][64]
#define W2B_OFF (128*64)                // [128][128]
#define W3B_OFF (W2B_OFF + 128*128)     // [512][128]
#define WS_SHORTS (W3B_OFF + 512*128)   // 90112 shorts

// ---- LDS layout (bytes), phase overlays
// region A (20224B): hb[16][72]@0 | z1b[16][136]@2304 | z2b[16][136]@6656 | A2[64][72]@11008
//                    -> dZ1[64][136]@0 -> pj[8][8][64]f32@0
#define SM_HB    0
#define SM_Z1    2304
#define SM_Z2    6656
#define SM_A2    11008
#define SM_DZ1   0
#define SM_PJ    0
// region B (17408B): Tsm[64][72] -> dZ2[64][136]
#define SM_T     20224
#define SM_DZ2   20224
#define SM_VT    37632      // bf16 [8][64][8]  Vt[e][n][j] = V_j[n]  (8192B)
#define SM_S1T   45824      // bf16 [128][8]    s1t[col][e] = sigmoid(a1)[e][col]
#define SM_S2T   47872      // bf16 [128][8]
#define SM_SIG   49920      // f32  [8][36]
#define SM_TOTAL 51072

typedef __attribute__((ext_vector_type(8))) short bf16x8;
typedef __attribute__((ext_vector_type(4))) float f32x4;

__device__ __forceinline__ float bf2f(unsigned int u16) {
    unsigned int x = u16 << 16;
    float f; __builtin_memcpy(&f, &x, 4); return f;
}
__device__ __forceinline__ unsigned short f2bf(float f) {
    unsigned int x; __builtin_memcpy(&x, &f, 4);
    x = (x + 0x7FFFu + ((x >> 16) & 1u)) >> 16;
    return (unsigned short)x;
}
__device__ __forceinline__ void unpack8(uint4 q, float* f) {
    f[0] = bf2f(q.x & 0xFFFFu); f[1] = bf2f(q.x >> 16);
    f[2] = bf2f(q.y & 0xFFFFu); f[3] = bf2f(q.y >> 16);
    f[4] = bf2f(q.z & 0xFFFFu); f[5] = bf2f(q.z >> 16);
    f[6] = bf2f(q.w & 0xFFFFu); f[7] = bf2f(q.w >> 16);
}
// fast fused softplus+sigmoid: one exp, one rcp, one log
__device__ __forceinline__ void sp_sig(float x, float& sp, float& sig) {
    float t = __expf(-fabsf(x));                    // e^{-|x|} in (0,1]
    float r = __builtin_amdgcn_rcpf(1.f + t);       // sigmoid(|x|)
    sig = (x >= 0.f) ? r : 1.f - r;
    sp  = fmaxf(x, 0.f) + __logf(1.f + t);
}
// fast tanh: (1-t)/(1+t), t=e^{-2|x|}, sign restored bitwise
__device__ __forceinline__ float tanh_fast(float x) {
    float t = __expf(-2.f * fabsf(x));
    float y = (1.f - t) * __builtin_amdgcn_rcpf(1.f + t);
    unsigned int xb, yb;
    __builtin_memcpy(&xb, &x, 4);
    __builtin_memcpy(&yb, &y, 4);
    yb |= (xb & 0x80000000u);
    float rr; __builtin_memcpy(&rr, &yb, 4);
    return rr;
}
__device__ __forceinline__ bf16x8 ldfrag(const unsigned short* p) {
    return *reinterpret_cast<const bf16x8*>(p);
}

// prep: bf16 copies of W1, W2, W3 in original [out][k] layout
__global__ void prep_weights(const float* __restrict__ W1,
                             const float* __restrict__ W2,
                             const float* __restrict__ W3,
                             unsigned short* __restrict__ wb) {
    int i = blockIdx.x * blockDim.x + threadIdx.x;
    if (i >= WS_SHORTS) return;
    float v;
    if (i < W2B_OFF) v = W1[i];
    else if (i < W3B_OFF) v = W2[i - W2B_OFF];
    else v = W3[i - W3B_OFF];
    wb[i] = f2bf(v);
}

__global__ __launch_bounds__(NTHREADS, 4)
void logncde_main(const float* __restrict__ hg,
                  const float* __restrict__ sigg,
                  const float* __restrict__ b1,
                  const float* __restrict__ b2,
                  const float* __restrict__ b3,
                  const unsigned short* __restrict__ wsb,
                  float* __restrict__ out) {
    __shared__ __align__(16) char sm[SM_TOTAL];
    unsigned short* hb  = (unsigned short*)(sm + SM_HB);   // [16][72] rows 8-15 garbage
    unsigned short* z1b = (unsigned short*)(sm + SM_Z1);   // [16][136]
    unsigned short* z2b = (unsigned short*)(sm + SM_Z2);   // [16][136]
    unsigned short* A2  = (unsigned short*)(sm + SM_A2);   // [64][72] block-diag c
    unsigned short* s1t = (unsigned short*)(sm + SM_S1T);  // [128][8]
    unsigned short* s2t = (unsigned short*)(sm + SM_S2T);  // [128][8]
    unsigned short* Vt  = (unsigned short*)(sm + SM_VT);   // [8][64][8]
    float*          sigs= (float*)(sm + SM_SIG);           // [8][36]
    unsigned short* Tsm = (unsigned short*)(sm + SM_T);    // [64][72]
    unsigned short* dZ1 = (unsigned short*)(sm + SM_DZ1);  // [64][136]
    unsigned short* dZ2 = (unsigned short*)(sm + SM_DZ2);  // [64][136]
    float*          pj  = (float*)(sm + SM_PJ);            // [8][8][64]

    const int tid = threadIdx.x;
    const int b0 = blockIdx.x * BT;

    const int lane = tid & 63;
    const int w = tid >> 6;            // wave id 0..7
    const int r16 = lane & 15;
    const int kb = lane >> 4;          // 0..3 fragment k-block
    const int crow = (lane >> 4) * 4;  // C fragment base row

    // ---- phase 0: load h + signatures
    {
        int e = tid >> 6, k = tid & 63;
        hb[e * 72 + k] = f2bf(hg[(b0 + e) * 64 + k]);
    }
    if (tid < BT * 36) {
        int e = tid / 36, j = tid % 36;
        sigs[e * 36 + j] = sigg[(b0 + e) * 36 + j];
    }
    __syncthreads();

    // ---- A2 build (needs sigs only; overlaps fwd1 phase):
    // A2[m=j*8+e][kidx=e'*8+i] = (e'==e) ? c[i][j]_e : 0, c antisymmetric.
    // Per wave: j = w (uniform), e = lane>>3, kg(e') = lane&7.
    {
        int e = lane >> 3, kg = lane & 7, j = w;
        uint4 q = {0u, 0u, 0u, 0u};
        if (kg == e) {
            unsigned short c8[8];
            #pragma unroll
            for (int i = 0; i < 8; ++i) {
                float v = 0.f;
                if (i < j) {
                    int p = 7 * i - i * (i - 1) / 2 + (j - i - 1);
                    v = sigs[e * 36 + 8 + p];
                } else if (i > j) {
                    int p = 7 * j - j * (j - 1) / 2 + (i - j - 1);
                    v = -sigs[e * 36 + 8 + p];
                }
                c8[i] = f2bf(v);
            }
            q.x = (unsigned int)c8[0] | ((unsigned int)c8[1] << 16);
            q.y = (unsigned int)c8[2] | ((unsigned int)c8[3] << 16);
            q.z = (unsigned int)c8[4] | ((unsigned int)c8[5] << 16);
            q.w = (unsigned int)c8[6] | ((unsigned int)c8[7] << 16);
        }
        int m = j * 8 + e;
        *reinterpret_cast<uint4*>(&A2[m * 72 + kg * 8]) = q;
    }

    // ---- fwd1 (MFMA): a1[8][128] = h @ W1^T; wave w -> 16-col tile w
    {
        f32x4 acc = {};
        const unsigned short* Ab = hb + r16 * 72 + kb * 8;
        const unsigned short* Bb = wsb + W1B_OFF + (w * 16 + r16) * 64 + kb * 8;
        #pragma unroll
        for (int ks = 0; ks < 2; ++ks) {
            acc = __builtin_amdgcn_mfma_f32_16x16x32_bf16(
                ldfrag(Ab + ks * 32), ldfrag(Bb + ks * 32), acc, 0, 0, 0);
        }
        if (lane < 32) {
            int col = w * 16 + r16;
            float bb = b1[col];
            unsigned short sp4[4];
            #pragma unroll
            for (int rr = 0; rr < 4; ++rr) {
                int e = crow + rr;
                float sp, sg;
                sp_sig(acc[rr] + bb, sp, sg);
                z1b[e * 136 + col] = f2bf(sp);
                sp4[rr] = f2bf(sg);
            }
            // one b64 write: s1t[col][crow..crow+3]
            uint2 qq;
            qq.x = (unsigned int)sp4[0] | ((unsigned int)sp4[1] << 16);
            qq.y = (unsigned int)sp4[2] | ((unsigned int)sp4[3] << 16);
            *reinterpret_cast<uint2*>(&s1t[col * 8 + crow]) = qq;
        }
    }
    __syncthreads();

    // ---- fwd2 (MFMA): a2 = z1 @ W2^T
    {
        f32x4 acc = {};
        const unsigned short* Ab = z1b + r16 * 136 + kb * 8;
        const unsigned short* Bb = wsb + W2B_OFF + (w * 16 + r16) * 128 + kb * 8;
        #pragma unroll
        for (int ks = 0; ks < 4; ++ks) {
            acc = __builtin_amdgcn_mfma_f32_16x16x32_bf16(
                ldfrag(Ab + ks * 32), ldfrag(Bb + ks * 32), acc, 0, 0, 0);
        }
        if (lane < 32) {
            int col = w * 16 + r16;
            float bb = b2[col];
            unsigned short sp4[4];
            #pragma unroll
            for (int rr = 0; rr < 4; ++rr) {
                int e = crow + rr;
                float sp, sg;
                sp_sig(acc[rr] + bb, sp, sg);
                z2b[e * 136 + col] = f2bf(sp);
                sp4[rr] = f2bf(sg);
            }
            uint2 qq;
            qq.x = (unsigned int)sp4[0] | ((unsigned int)sp4[1] << 16);
            qq.y = (unsigned int)sp4[2] | ((unsigned int)sp4[3] << 16);
            *reinterpret_cast<uint2*>(&s2t[col * 8 + crow]) = qq;
        }
    }
    __syncthreads();

    // ---- fwd3 (MFMA): V = tanh(z2 @ W3^T + b3); wave w = field j, cols w*64..
    {
        f32x4 acc[4] = {};
        const unsigned short* Ab = z2b + r16 * 136 + kb * 8;
        const unsigned short* Bb = wsb + W3B_OFF + kb * 8;
        #pragma unroll
        for (int ks = 0; ks < 4; ++ks) {
            bf16x8 a = ldfrag(Ab + ks * 32);
            #pragma unroll
            for (int nt = 0; nt < 4; ++nt) {
                bf16x8 b = ldfrag(Bb + (w * 64 + nt * 16 + r16) * 128 + ks * 32);
                acc[nt] = __builtin_amdgcn_mfma_f32_16x16x32_bf16(a, b, acc[nt], 0, 0, 0);
            }
        }
        if (lane < 32) {
            #pragma unroll
            for (int nt = 0; nt < 4; ++nt) {
                int c = w * 64 + nt * 16 + r16;
                float bb = b3[c];
                int n = c & 63;
                #pragma unroll
                for (int rr = 0; rr < 4; ++rr) {
                    int e = crow + rr;
                    Vt[(e * 64 + n) * 8 + w] = f2bf(tanh_fast(acc[nt][rr] + bb));
                }
            }
        }
    }
    __syncthreads();

    // ---- T-build (MFMA): T[64][64] = A2[64][64] @ Vt-as-B. k-order: kidx = e'*8+i,
    //      so B[n][kidx..kidx+7] = Vt[e'][n][0..7] (one contiguous bf16x8).
    {
        int mt = w & 3, nh = w >> 2;
        f32x4 acc[2] = {};
        const unsigned short* Ab = A2 + (mt * 16 + r16) * 72 + kb * 8;
        #pragma unroll
        for (int ks = 0; ks < 2; ++ks) {
            bf16x8 a = ldfrag(Ab + ks * 32);
            int ep = ks * 4 + kb;
            #pragma unroll
            for (int nt = 0; nt < 2; ++nt) {
                int n = nh * 32 + nt * 16 + r16;
                bf16x8 b = ldfrag(&Vt[(ep * 64 + n) * 8]);
                acc[nt] = __builtin_amdgcn_mfma_f32_16x16x32_bf16(a, b, acc[nt], 0, 0, 0);
            }
        }
        #pragma unroll
        for (int nt = 0; nt < 2; ++nt) {
            int col = nh * 32 + nt * 16 + r16;
            #pragma unroll
            for (int rr = 0; rr < 4; ++rr) {
                int row = mt * 16 + crow + rr;
                Tsm[row * 72 + col] = f2bf(acc[nt][rr]);
            }
        }
    }
    __syncthreads();

    // ---- jvp1 (MFMA): dA1[64][128] = T @ W1^T; mask s1 -> dZ1
    {
        int mt = w & 3, nh = w >> 2;
        f32x4 acc[4] = {};
        const unsigned short* Ab = Tsm + (mt * 16 + r16) * 72 + kb * 8;
        const unsigned short* Bb = wsb + W1B_OFF + kb * 8;
        #pragma unroll
        for (int ks = 0; ks < 2; ++ks) {
            bf16x8 a = ldfrag(Ab + ks * 32);
            #pragma unroll
            for (int nt = 0; nt < 4; ++nt) {
                int n = nh * 64 + nt * 16 + r16;
                bf16x8 b = ldfrag(Bb + n * 64 + ks * 32);
                acc[nt] = __builtin_amdgcn_mfma_f32_16x16x32_bf16(a, b, acc[nt], 0, 0, 0);
            }
        }
        int ebase = crow & 7;
        #pragma unroll
        for (int nt = 0; nt < 4; ++nt) {
            int col = nh * 64 + nt * 16 + r16;
            uint2 qq = *reinterpret_cast<const uint2*>(&s1t[col * 8 + ebase]);
            float s4[4];
            s4[0] = bf2f(qq.x & 0xFFFFu); s4[1] = bf2f(qq.x >> 16);
            s4[2] = bf2f(qq.y & 0xFFFFu); s4[3] = bf2f(qq.y >> 16);
            #pragma unroll
            for (int rr = 0; rr < 4; ++rr) {
                int row = mt * 16 + crow + rr;
                dZ1[row * 136 + col] = f2bf(acc[nt][rr] * s4[rr]);
            }
        }
    }
    __syncthreads();

    // ---- jvp2 (MFMA): dA2 = dZ1 @ W2^T; mask s2 -> dZ2
    {
        int mt = w & 3, nh = w >> 2;
        f32x4 acc[4] = {};
        const unsigned short* Ab = dZ1 + (mt * 16 + r16) * 136 + kb * 8;
        const unsigned short* Bb = wsb + W2B_OFF + kb * 8;
        #pragma unroll
        for (int ks = 0; ks < 4; ++ks) {
            bf16x8 a = ldfrag(Ab + ks * 32);
            #pragma unroll
            for (int nt = 0; nt < 4; ++nt) {
                int n = nh * 64 + nt * 16 + r16;
                bf16x8 b = ldfrag(Bb + n * 128 + ks * 32);
                acc[nt] = __builtin_amdgcn_mfma_f32_16x16x32_bf16(a, b, acc[nt], 0, 0, 0);
            }
        }
        int ebase = crow & 7;
        #pragma unroll
        for (int nt = 0; nt < 4; ++nt) {
            int col = nh * 64 + nt * 16 + r16;
            uint2 qq = *reinterpret_cast<const uint2*>(&s2t[col * 8 + ebase]);
            float s4[4];
            s4[0] = bf2f(qq.x & 0xFFFFu); s4[1] = bf2f(qq.x >> 16);
            s4[2] = bf2f(qq.y & 0xFFFFu); s4[3] = bf2f(qq.y >> 16);
            #pragma unroll
            for (int rr = 0; rr < 4; ++rr) {
                int row = mt * 16 + crow + rr;
                dZ2[row * 136 + col] = f2bf(acc[nt][rr] * s4[rr]);
            }
        }
    }
    __syncthreads();

    // ---- jvp3 (MFMA): wave w = field j; masked by tanh' -> pj[j][e][n']
    {
        int j = w;
        int mt = j >> 1, half = j & 1;
        f32x4 acc[4] = {};
        const unsigned short* Ab = dZ2 + (mt * 16 + r16) * 136 + kb * 8;
        const unsigned short* Bb = wsb + W3B_OFF + (j * 64) * 128 + kb * 8;
        #pragma unroll
        for (int ks = 0; ks < 4; ++ks) {
            bf16x8 a = ldfrag(Ab + ks * 32);
            #pragma unroll
            for (int nt = 0; nt < 4; ++nt) {
                bf16x8 b = ldfrag(Bb + (nt * 16 + r16) * 128 + ks * 32);
                acc[nt] = __builtin_amdgcn_mfma_f32_16x16x32_bf16(a, b, acc[nt], 0, 0, 0);
            }
        }
        if ((crow >> 3) == half) {
            #pragma unroll
            for (int nt = 0; nt < 4; ++nt) {
                int np = nt * 16 + r16;
                #pragma unroll
                for (int rr = 0; rr < 4; ++rr) {
                    int e = (crow + rr) & 7;
                    float v = bf2f(Vt[(e * 64 + np) * 8 + j]);
                    pj[(j * 8 + e) * 64 + np] = (1.f - v * v) * acc[nt][rr];
                }
            }
        }
    }
    __syncthreads();

    // ---- reduce: out[e][n'] = sum_i sig1[i] V_i[n'] + sum_j pj[j][e][n']
    {
        int e = tid >> 6, np = tid & 63;
        uint4 q = *reinterpret_cast<const uint4*>(&Vt[(e * 64 + np) * 8]);
        float v8[8]; unpack8(q, v8);
        float s = 0.f;
        #pragma unroll
        for (int j = 0; j < 8; ++j) s += pj[(j * 8 + e) * 64 + np];
        float l1 = 0.f;
        #pragma unroll
        for (int i = 0; i < 8; ++i) l1 += sigs[e * 36 + i] * v8[i];
        out[(b0 + e) * 64 + np] = l1 + s;
    }
}

extern "C" void kernel_launch(void* const* d_in, const int* in_sizes, int n_in,
                              void* d_out, int out_size, void* d_ws, size_t ws_size,
                              hipStream_t stream) {
    const float* hg  = (const float*)d_in[0];
    const float* sg  = (const float*)d_in[1];
    const float* W1  = (const float*)d_in[2];
    const float* b1  = (const float*)d_in[3];
    const float* W2  = (const float*)d_in[4];
    const float* b2  = (const float*)d_in[5];
    const float* W3  = (const float*)d_in[6];
    const float* b3  = (const float*)d_in[7];
    float* outp = (float*)d_out;
    unsigned short* wsb = (unsigned short*)d_ws;

    hipLaunchKernelGGL(prep_weights, dim3((WS_SHORTS + 255) / 256), dim3(256), 0, stream,
                       W1, W2, W3, wsb);
    hipLaunchKernelGGL(logncde_main, dim3(BATCH / BT), dim3(NTHREADS), 0, stream,
                       hg, sg, b1, b2, b3, wsb, outp);
}